// Round 4
// baseline (119.032 us; speedup 1.0000x reference)
//
#include <hip/hip_runtime.h>

#define BH  64
#define SEQ 4096
#define DH  64

// ---------------------------------------------------------------------------
// Kernel 1: partial kv = k^T v over a chunk of S rows. One (b,h,chunk)/block.
// 128 threads = 2 waves. Thread tile 4(d) x 8(e): 16 d-groups x 8 e-groups.
// Per staged s-row per thread: 3 ds_read_b128 (36 cyc) + 32 FMA (64 cyc)
// -> VALU-bound. LDS 16 KB -> 10 blocks (20 waves)/CU.
// ---------------------------------------------------------------------------
__global__ __launch_bounds__(128) void kv_partial_kernel(
    const float* __restrict__ k, const float* __restrict__ v,
    float* __restrict__ partial, int nchunk, int rows_per_chunk) {
  const int t = threadIdx.x;
  const int bh = blockIdx.x / nchunk;
  const int chunk = blockIdx.x - bh * nchunk;

  const float* kb = k + (size_t)bh * SEQ * DH + (size_t)chunk * rows_per_chunk * DH;
  const float* vb = v + (size_t)bh * SEQ * DH + (size_t)chunk * rows_per_chunk * DH;

  __shared__ float ks[32 * 64];
  __shared__ float vs[32 * 64];

  const int d0 = (t & 15) * 4;   // 16 d-groups of 4
  const int e0 = (t >> 4) * 8;   // 8 e-groups of 8

  float acc[4][8];
#pragma unroll
  for (int i = 0; i < 4; ++i)
#pragma unroll
    for (int j = 0; j < 8; ++j) acc[i][j] = 0.f;

  for (int t0 = 0; t0 < rows_per_chunk; t0 += 32) {
    // stage 32 rows of k and v (8 KB each = 512 float4), coalesced
    const float4* gk4 = (const float4*)(kb + (size_t)t0 * DH);
    const float4* gv4 = (const float4*)(vb + (size_t)t0 * DH);
    float4* ks4 = (float4*)ks;
    float4* vs4 = (float4*)vs;
#pragma unroll
    for (int j = 0; j < 4; ++j) {
      ks4[t + j * 128] = gk4[t + j * 128];
      vs4[t + j * 128] = gv4[t + j * 128];
    }
    __syncthreads();

    for (int r8 = 0; r8 < 32; r8 += 8) {
#pragma unroll
      for (int rr = 0; rr < 8; ++rr) {
        const int r = r8 + rr;
        float4 kav = *(const float4*)&ks[r * 64 + d0];
        float4 v0  = *(const float4*)&vs[r * 64 + e0];
        float4 v1  = *(const float4*)&vs[r * 64 + e0 + 4];
        float ka[4] = {kav.x, kav.y, kav.z, kav.w};
        float va[8] = {v0.x, v0.y, v0.z, v0.w, v1.x, v1.y, v1.z, v1.w};
#pragma unroll
        for (int i = 0; i < 4; ++i)
#pragma unroll
          for (int j = 0; j < 8; ++j) acc[i][j] += ka[i] * va[j];
      }
    }
    __syncthreads();
  }

  float* pb = partial + (size_t)blockIdx.x * (DH * DH);
#pragma unroll
  for (int i = 0; i < 4; ++i) {
    float4 w0 = {acc[i][0], acc[i][1], acc[i][2], acc[i][3]};
    float4 w1 = {acc[i][4], acc[i][5], acc[i][6], acc[i][7]};
    *(float4*)&pb[(d0 + i) * 64 + e0]     = w0;
    *(float4*)&pb[(d0 + i) * 64 + e0 + 4] = w1;
  }
}

// ---------------------------------------------------------------------------
// Kernel 2: reduce partials -> kvf [BH][64*64]. Fully coalesced float4.
// Grid: 256 blocks x 256 threads covers 65536 float4 slots.
// ---------------------------------------------------------------------------
__global__ __launch_bounds__(256) void kv_reduce_kernel(
    const float* __restrict__ partial, float* __restrict__ kvf, int nchunk) {
  const int gid = blockIdx.x * 256 + threadIdx.x;
  const int bh = gid >> 10;
  const int idx = gid & 1023;
  float4 s = {0.f, 0.f, 0.f, 0.f};
  for (int c = 0; c < nchunk; ++c) {
    const float4* p = (const float4*)(partial + ((size_t)bh * nchunk + c) * (DH * DH));
    float4 x = p[idx];
    s.x += x.x; s.y += x.y; s.z += x.z; s.w += x.w;
  }
  ((float4*)kvf)[gid] = s;
}

// ---------------------------------------------------------------------------
// Kernel 3: out = q @ kv. kv staged in LDS (16 KB, broadcast reads, 2-way
// conflicts only). q read global->reg (rows' cache lines fully consumed
// across the d-loop, L1-resident). Thread: 4 rows (stride 64) x 16 cols.
// Per d-step (4 d): 4 q loads + 16 ds_read_b128 vs 256 FMA -> VALU-bound.
// Block = 256 rows; grid = 64 heads x 16.
// ---------------------------------------------------------------------------
__global__ __launch_bounds__(256) void out_kernel(
    const float* __restrict__ q, const float* __restrict__ kvf,
    float* __restrict__ out) {
  const int t = threadIdx.x;
  const int bh = blockIdx.x >> 4;
  const int rb = blockIdx.x & 15;
  const int row_base = rb * 256;

  __shared__ float kv_lds[64 * 64];

  // stage kv (16 KB = 1024 float4), coalesced
  const float4* gkv4 = (const float4*)(kvf + (size_t)bh * (DH * DH));
  float4* kv4 = (float4*)kv_lds;
#pragma unroll
  for (int j = 0; j < 4; ++j) kv4[t + j * 256] = gkv4[t + j * 256];
  __syncthreads();

  const int r0 = t >> 2;          // 0..63
  const int c0 = (t & 3) * 16;    // 4 col-groups of 16

  const float* qb = q + (size_t)bh * SEQ * DH + (size_t)(row_base + r0) * DH;

  float acc[4][16];
#pragma unroll
  for (int i = 0; i < 4; ++i)
#pragma unroll
    for (int j = 0; j < 16; ++j) acc[i][j] = 0.f;

  for (int ds = 0; ds < 16; ++ds) {
    const int d0 = ds * 4;
    float4 qv[4];
#pragma unroll
    for (int ri = 0; ri < 4; ++ri)
      qv[ri] = *(const float4*)&qb[ri * 64 * DH + d0];
#pragma unroll
    for (int dd = 0; dd < 4; ++dd) {
      const float* kr = &kv_lds[(d0 + dd) * DH + c0];
      float4 k0 = *(const float4*)&kr[0];
      float4 k1 = *(const float4*)&kr[4];
      float4 k2 = *(const float4*)&kr[8];
      float4 k3 = *(const float4*)&kr[12];
#pragma unroll
      for (int ri = 0; ri < 4; ++ri) {
        const float qs = (dd == 0) ? qv[ri].x : (dd == 1) ? qv[ri].y
                       : (dd == 2) ? qv[ri].z : qv[ri].w;
        acc[ri][0]  += qs * k0.x; acc[ri][1]  += qs * k0.y;
        acc[ri][2]  += qs * k0.z; acc[ri][3]  += qs * k0.w;
        acc[ri][4]  += qs * k1.x; acc[ri][5]  += qs * k1.y;
        acc[ri][6]  += qs * k1.z; acc[ri][7]  += qs * k1.w;
        acc[ri][8]  += qs * k2.x; acc[ri][9]  += qs * k2.y;
        acc[ri][10] += qs * k2.z; acc[ri][11] += qs * k2.w;
        acc[ri][12] += qs * k3.x; acc[ri][13] += qs * k3.y;
        acc[ri][14] += qs * k3.z; acc[ri][15] += qs * k3.w;
      }
    }
  }

  float* ob = out + (size_t)bh * SEQ * DH + (size_t)(row_base + r0) * DH + c0;
#pragma unroll
  for (int ri = 0; ri < 4; ++ri) {
#pragma unroll
    for (int j = 0; j < 4; ++j) {
      float4 w = {acc[ri][4 * j + 0], acc[ri][4 * j + 1],
                  acc[ri][4 * j + 2], acc[ri][4 * j + 3]};
      *(float4*)&ob[(size_t)ri * 64 * DH + 4 * j] = w;
    }
  }
}

// ---------------------------------------------------------------------------
extern "C" void kernel_launch(void* const* d_in, const int* in_sizes, int n_in,
                              void* d_out, int out_size, void* d_ws, size_t ws_size,
                              hipStream_t stream) {
  const float* q = (const float*)d_in[0];
  const float* k = (const float*)d_in[1];
  const float* v = (const float*)d_in[2];
  float* out = (float*)d_out;

  float* kvf = (float*)d_ws;                      // [BH][64*64] = 1 MB
  float* partial = kvf + (size_t)BH * DH * DH;    // [BH*nchunk][64*64]

  int nchunk = 32;
  const size_t head_mat = (size_t)BH * DH * DH * sizeof(float);  // 1 MB
  while (nchunk > 1 && ws_size < head_mat * (size_t)(nchunk + 1)) nchunk >>= 1;
  int rows = SEQ / nchunk;

  hipLaunchKernelGGL(kv_partial_kernel, dim3(BH * nchunk), dim3(128), 0, stream,
                     k, v, partial, nchunk, rows);
  hipLaunchKernelGGL(kv_reduce_kernel, dim3(256), dim3(256), 0, stream,
                     partial, kvf, nchunk);
  hipLaunchKernelGGL(out_kernel, dim3(BH * 16), dim3(256), 0, stream,
                     q, kvf, out);
}